// Round 2
// baseline (752.680 us; speedup 1.0000x reference)
//
#include <hip/hip_runtime.h>

// Problem: relu(quant8(x) @ quant8(W)^T + bias)
//   x: [2,2048,4096] f32  -> M=4096, K=4096
//   W: [16384,4096]  f32  -> N=16384 (row-major in K, i.e. B^T layout)
//   out: [2,2048,16384] f32
//
// R3 change: LDS-bandwidth wall fix. R2 counters: MfmaUtil 37%, VALU 15%,
// bank-conflict 0, HBM 22% -> missing ~50% of cycles. Audit: per K-tile per
// CU the LDS moved 288 KB (224 KB ds_read + 64 KB global_load_lds writes)
// ~= 2300-3400 cy at measured b128 rates, vs the 2613-cy MFMA floor: LDS
// and MFMA pipes were co-saturated and partially serialized.
// Fix: B never touches LDS. quantize_pack_b writes qB in MFMA-fragment
// order (one 16x64 frag = 64 lanes x 16 B = 1024 B contiguous), and the
// GEMM loads B-frags global->VGPR as coalesced dwordx4 with one-phase
// prefetch lead. LDS/K-tile: 288 KB -> 160 KB (A only); LDS 128->64 KiB.
//
// Schedule per K-tile (4 phases), quadrants q(qm,qn) in order 00,01,10,11:
//   ph1: ds_read A0 (8xb128); load b1(T) (4xdwordx4);  MFMA q00 (a0*b0)
//   ph2: stage A0(T+2) (2 GLL);                        MFMA q01 (a0*b1)
//   ph3: ds_read A1 (8xb128);                          MFMA q10 (a1*b0)
//   ph4: load b0(T+1); stage A1(T+2); vmcnt(12);       MFMA q11 (a1*b1)
// each phase: [reads/stages]; barrier; lgkm; setprio(1); MFMA; setprio(0); barrier
// vmcnt(12) = exactly this group's 12 vm ops {b1:4, GLL:2, b0:4, GLL:2} ->
// everything older (incl. tile T+1's A stages) retired; never drains to 0.
// Group NT-2 stages nothing -> vmcnt(8); last group needs no pacing wait.
// A-side LDS XOR swizzle (R1, conflict=0) unchanged.

#define HIDDEN 4096
#define INTER 16384
#define MDIM 4096
#define BK 128
#define NT (HIDDEN / BK)   // 32 K-tiles

typedef int v4i __attribute__((ext_vector_type(4)));

// ---------------------------------------------------------------------------
// Quantize A: q = round_ne(clamp(x, -c, c) * 127/c), packed 4 int8 per int32,
// linear layout (A is LDS-staged in the GEMM).
// ---------------------------------------------------------------------------
__global__ __launch_bounds__(256) void quantize_kernel(
    const float* __restrict__ x,
    signed char* __restrict__ q,
    const float* __restrict__ clip_ptr,
    int n4)
{
    int i = blockIdx.x * blockDim.x + threadIdx.x;
    if (i >= n4) return;
    float c = fabsf(clip_ptr[0]);
    float inv_scale = 127.0f / c;
    float4 v = reinterpret_cast<const float4*>(x)[i];
    int q0 = __float2int_rn(fminf(fmaxf(v.x, -c), c) * inv_scale);
    int q1 = __float2int_rn(fminf(fmaxf(v.y, -c), c) * inv_scale);
    int q2 = __float2int_rn(fminf(fmaxf(v.z, -c), c) * inv_scale);
    int q3 = __float2int_rn(fminf(fmaxf(v.w, -c), c) * inv_scale);
    int pack = (q0 & 0xff) | ((q1 & 0xff) << 8) | ((q2 & 0xff) << 16) | (q3 << 24);
    reinterpret_cast<int*>(q)[i] = pack;
}

// ---------------------------------------------------------------------------
// Quantize + pack B into MFMA-fragment order.
// Frag (nf = n>>4, kf = k>>6) is 1024 B: lane l = (n&15) | (((k>>4)&3)<<4)
// holds bytes k&15..+15. Element (n,k) -> byte offset:
//   ((n>>4)<<16) | ((k>>6)<<10) | (((k>>4)&3)<<8) | ((n&15)<<4) | (k&15)
// Thread i handles (n = i>>10, k = (i&1023)*4): f32 reads stay perfectly
// coalesced (same linear float4 index as before); the 4 packed bytes stay
// within one lane slot (k%4==0), 4-byte-aligned int store.
// ---------------------------------------------------------------------------
__global__ __launch_bounds__(256) void quantize_pack_b_kernel(
    const float* __restrict__ x,
    signed char* __restrict__ qp,
    const float* __restrict__ clip_ptr,
    int n4)
{
    int i = blockIdx.x * blockDim.x + threadIdx.x;
    if (i >= n4) return;
    float c = fabsf(clip_ptr[0]);
    float inv_scale = 127.0f / c;
    float4 v = reinterpret_cast<const float4*>(x)[i];
    int q0 = __float2int_rn(fminf(fmaxf(v.x, -c), c) * inv_scale);
    int q1 = __float2int_rn(fminf(fmaxf(v.y, -c), c) * inv_scale);
    int q2 = __float2int_rn(fminf(fmaxf(v.z, -c), c) * inv_scale);
    int q3 = __float2int_rn(fminf(fmaxf(v.w, -c), c) * inv_scale);
    int pack = (q0 & 0xff) | ((q1 & 0xff) << 8) | ((q2 & 0xff) << 16) | (q3 << 24);
    int n = i >> 10;              // row (HIDDEN/4 = 1024 groups per row)
    int k = (i & 1023) << 2;      // column of first element
    size_t addr = ((size_t)(n >> 4) << 16) | ((size_t)(k >> 6) << 10)
                | ((size_t)((k >> 4) & 3) << 8) | ((size_t)(n & 15) << 4)
                | (size_t)(k & 15);
    *reinterpret_cast<int*>(qp + addr) = pack;
}

// ---------------------------------------------------------------------------
// i8 GEMM, 256x256 tile, 512 threads = 8 waves (2M x 4N).
// Per wave: 128 M-rows x 64 N-cols as 2(qm) x 2(qn) x 4(m) x 2(n) 16x16 frags.
// A: LDS double-buffered (2 x 32 KiB). B: direct global->VGPR from packed qB.
// ---------------------------------------------------------------------------

#define GLL(src, dst) __builtin_amdgcn_global_load_lds( \
    (const __attribute__((address_space(1))) void*)(src), \
    (__attribute__((address_space(3))) void*)(dst), 16, 0, 0)

// one A half-tile = 128 rows x 128 B = 2 issues of (512 threads x 16 B)
#define STAGE(gptr, lptr) do { \
    GLL((gptr), (lptr)); \
    GLL((gptr) + (size_t)64 * HIDDEN, (lptr) + 8192); } while (0)

#define BARX() __builtin_amdgcn_s_barrier()
#define LGKM0() asm volatile("s_waitcnt lgkmcnt(0)" ::: "memory")
#define VM12() asm volatile("s_waitcnt vmcnt(12)" ::: "memory")
#define VM8() asm volatile("s_waitcnt vmcnt(8)" ::: "memory")
#define VMNOP()
#define PRIO1() __builtin_amdgcn_s_setprio(1)
#define PRIO0() __builtin_amdgcn_s_setprio(0)

#define READ_A(cb, qm) do { _Pragma("unroll") \
    for (int m_ = 0; m_ < 4; m_++) { \
      const signed char* p_ = &As[cb][(qm) * 16384 + aOff + m_ * 2048]; \
      a[m_][0] = *reinterpret_cast<const v4i*>(p_ + c0); \
      a[m_][1] = *reinterpret_cast<const v4i*>(p_ + c1); } } while (0)

// b-frags for quadrant-column qn of tile with kf0 = T*2: 4 coalesced dwordx4.
#define LOADB(dst, qn, kf0) do { _Pragma("unroll") \
    for (int n_ = 0; n_ < 2; n_++) { _Pragma("unroll") \
      for (int kk_ = 0; kk_ < 2; kk_++) { \
        dst[n_][kk_] = *reinterpret_cast<const v4i*>( \
            bpw + (((size_t)((qn) * 8 + n_) << 16) | \
                   ((size_t)((kf0) + kk_) << 10)) + L16); } } } while (0)

// 16 MFMA, k0-sweep then k1-sweep (keeps dependent pairs 8 apart).
#define MFMA_Q(qm, qn, bset) do { _Pragma("unroll") \
    for (int m_ = 0; m_ < 4; m_++) { _Pragma("unroll") \
      for (int n_ = 0; n_ < 2; n_++) \
        acc[qm][qn][m_][n_] = __builtin_amdgcn_mfma_i32_16x16x64_i8( \
            a[m_][0], bset[n_][0], acc[qm][qn][m_][n_], 0, 0, 0); } \
    _Pragma("unroll") \
    for (int m_ = 0; m_ < 4; m_++) { _Pragma("unroll") \
      for (int n_ = 0; n_ < 2; n_++) \
        acc[qm][qn][m_][n_] = __builtin_amdgcn_mfma_i32_16x16x64_i8( \
            a[m_][1], bset[n_][1], acc[qm][qn][m_][n_], 0, 0, 0); } } while (0)

// One K-tile group. cb = LDS buffer of tile T (= T&1).
// S2: stage A(T+2).  SB: load b0(T+1) at ph4.  VMW: pacing wait at ph4.
#define GROUP(cb, T, S2, SB, VMW) do { \
    /* ph1: q00 (a0*b0); read A0; prefetch b1(T) */ \
    READ_A(cb, 0); \
    LOADB(b1, 1, (T) * 2); \
    BARX(); LGKM0(); PRIO1(); MFMA_Q(0, 0, b0); PRIO0(); BARX(); \
    /* ph2: q01 (a0*b1); A0 region retired -> stage A0(T+2) */ \
    if (S2) STAGE(gA + (size_t)((T) + 2) * BK, &As[cb][0] + ldsT); \
    BARX(); PRIO1(); MFMA_Q(0, 1, b1); PRIO0(); BARX(); \
    /* ph3: q10 (a1*b0); read A1 */ \
    READ_A(cb, 1); \
    BARX(); LGKM0(); PRIO1(); MFMA_Q(1, 0, b0); PRIO0(); BARX(); \
    /* ph4: q11 (a1*b1); prefetch b0(T+1); A1 retired -> stage A1(T+2) */ \
    if (SB) LOADB(b0, 0, ((T) + 1) * 2); \
    if (S2) STAGE(gA + (size_t)128 * HIDDEN + (size_t)((T) + 2) * BK, \
                  &As[cb][16384] + ldsT); \
    VMW(); \
    BARX(); PRIO1(); MFMA_Q(1, 1, b1); PRIO0(); BARX(); \
  } while (0)

__global__ __launch_bounds__(512, 2) void gemm_i8_kernel(
    const signed char* __restrict__ qA,   // [MDIM, HIDDEN] linear
    const signed char* __restrict__ Bp,   // packed frag-order [1024][64][1024B]
    const float* __restrict__ bias,       // [INTER]
    const float* __restrict__ wclip,
    const float* __restrict__ iclip,
    float* __restrict__ out)              // [MDIM, INTER]
{
    // A only, double-buffered: 2 x 32 KiB = 64 KiB
    __shared__ __align__(16) signed char As[2][32768];

    const int t = threadIdx.x;
    const int L = t & 63;
    const int W = t >> 6;          // wave 0..7
    const int wm = W >> 2;         // 0..1
    const int wn = W & 3;          // 0..3
    const int lane16 = L & 15;
    const int quad = L >> 4;
    const int swz = lane16 & 7;
    const int L16 = L * 16;

    // XCD-aware bijective swizzle (nwg = 1024, 1024 % 8 == 0)
    int wg = blockIdx.y * 64 + blockIdx.x;
    wg = (wg & 7) * 128 + (wg >> 3);
    const int mBase = (wg >> 6) * 256;
    const int nBase = (wg & 63) * 256;

    // A staging: thread t covers row (t>>3), physical chunk (t&7); source
    // column pre-swizzled (logical chunk = (t&7) ^ (row&7)).
    const int sRow = t >> 3;                         // 0..63
    const int sColSwz = ((t & 7) ^ (sRow & 7)) * 16;
    const signed char* gA = qA + (size_t)(mBase + sRow) * HIDDEN + sColSwz;
    const int ldsT = t * 16;

    // A fragment read offsets (row&7 == lane16&7 for every fragment row).
    const int aOff = (wm * 64 + lane16) * 128;
    const int c0 = (quad ^ swz) * 16;
    const int c1 = ((quad + 4) ^ swz) * 16;

    // packed-B wave base: nf = nBase/16 + qn*8 + wn*2 + n
    const signed char* bpw = Bp + ((size_t)((nBase >> 4) + wn * 2) << 16);

    v4i acc[2][2][4][2];
#pragma unroll
    for (int i = 0; i < 2; i++)
#pragma unroll
        for (int j = 0; j < 2; j++)
#pragma unroll
            for (int m = 0; m < 4; m++)
#pragma unroll
                for (int n = 0; n < 2; n++)
                    acc[i][j][m][n] = (v4i){0, 0, 0, 0};

    v4i a[4][2], b0[2][2], b1[2][2];

    // Prologue: stage A tiles 0 and 1 (8 GLL), prefetch b0(tile0).
    // vmcnt(8) retires tile0's 4 GLL; tile1's 4 GLL + 4 b-loads stay in flight.
    STAGE(gA, &As[0][0] + ldsT);                                   // t0-A0
    STAGE(gA + (size_t)128 * HIDDEN, &As[0][16384] + ldsT);        // t0-A1
    STAGE(gA + BK, &As[1][0] + ldsT);                              // t1-A0
    STAGE(gA + (size_t)128 * HIDDEN + BK, &As[1][16384] + ldsT);   // t1-A1
    LOADB(b0, 0, 0);
    VM8();
    BARX();

    // Main loop: groups 0..29 fully pipelined (vmcnt never drained).
    for (int T = 0; T < NT - 2; T += 2) {
        GROUP(0, T,     1, 1, VM12);
        GROUP(1, T + 1, 1, 1, VM12);
    }
    // Group NT-2: no staging left -> tighter pacing guards A(NT-1).
    GROUP(0, NT - 2, 0, 1, VM8);
    // Last group: nothing in flight to pace.
    GROUP(1, NT - 1, 0, 0, VMNOP);

    // Epilogue: out = relu(acc * (|wc|/127)*(|ic|/127) + bias)
    const float scale = (fabsf(wclip[0]) / 127.0f) * (fabsf(iclip[0]) / 127.0f);

    float bv[2][2];
#pragma unroll
    for (int qn = 0; qn < 2; qn++)
#pragma unroll
        for (int n = 0; n < 2; n++)
            bv[qn][n] = bias[nBase + qn * 128 + wn * 32 + n * 16 + lane16];

    // C/D mapping (guide-verified, dtype-independent): col = lane&15,
    // row = quad*4 + reg.
#pragma unroll
    for (int qm = 0; qm < 2; qm++)
#pragma unroll
        for (int m = 0; m < 4; m++)
#pragma unroll
            for (int r = 0; r < 4; r++) {
                const int row = mBase + qm * 128 + wm * 64 + m * 16 + quad * 4 + r;
                float* orow = out + (size_t)row * INTER + nBase + wn * 32 + lane16;
#pragma unroll
                for (int qn = 0; qn < 2; qn++)
#pragma unroll
                    for (int n = 0; n < 2; n++) {
                        float v = (float)acc[qm][qn][m][n][r] * scale + bv[qn][n];
                        orow[qn * 128 + n * 16] = fmaxf(v, 0.0f);
                    }
            }
}

extern "C" void kernel_launch(void* const* d_in, const int* in_sizes, int n_in,
                              void* d_out, int out_size, void* d_ws, size_t ws_size,
                              hipStream_t stream) {
    const float* hidden_states  = (const float*)d_in[0];  // [2,2048,4096]
    const float* weight         = (const float*)d_in[1];  // [16384,4096]
    const float* bias           = (const float*)d_in[2];  // [16384]
    const float* weight_clip    = (const float*)d_in[3];  // scalar
    const float* input_clip     = (const float*)d_in[4];  // scalar
    float* out = (float*)d_out;

    signed char* qA = (signed char*)d_ws;                         // 16 MiB
    signed char* Bp = qA + (size_t)MDIM * HIDDEN;                 // 64 MiB packed

    // Quantize activations (linear): 4096*4096 / 4 elems per thread
    {
        int n4 = MDIM * HIDDEN / 4;
        quantize_kernel<<<n4 / 256, 256, 0, stream>>>(hidden_states, qA, input_clip, n4);
    }
    // Quantize + pack weights: 16384*4096 / 4
    {
        int n4 = INTER * HIDDEN / 4;
        quantize_pack_b_kernel<<<n4 / 256, 256, 0, stream>>>(weight, Bp, weight_clip, n4);
    }

    dim3 grid(INTER / 256, MDIM / 256);   // 64 x 16 = 1024 blocks
    gemm_i8_kernel<<<grid, 512, 0, stream>>>(qA, Bp, bias, weight_clip, input_clip, out);
}